// Round 5
// baseline (357.914 us; speedup 1.0000x reference)
//
#include <hip/hip_runtime.h>
#include <hip/hip_bf16.h>
#include <hip/hip_fp16.h>

#define N_NODES 100000
#define N_EDGES 3200000
#define N_GRAPHS 4096
#define N_REL 5
#define N_BASES 4
#define HID 32
#define SEG (N_NODES*N_REL)
#define DUMMY N_NODES            // extra node whose fp16 feature row is all-zero

#define BNODE 196                // dst nodes per bucket
#define NBUCK 511                // ceil(100000/196)
#define BCAP  7168               // part-record capacity per bucket (mean 6272)
#define PBCAP 10752              // padded srcs capacity per bucket (mean ~9.4K)
#define NKEY  980                // 196 nodes * 5 rels
#define PTILE 4096               // edges per k_part block

#define KDIM 192                 // MFMA K: 5 rel means * 32 + 32 self
#define ASTR 208                 // sAgg row stride in halves (416 B: 16B-aligned)

typedef _Float16 half8 __attribute__((ext_vector_type(8)));
typedef float floatx4 __attribute__((ext_vector_type(4)));

// ---------------- CSR pass 1: partition edges into dst-range buckets ----------------
// Single LDS-atomic pass: atomicAdd RETURNS the within-block rank, so the
// second cursor-atomic pass is gone. meta packs bb(9b)|rank(12b)|lkey(10b).
static __global__ __launch_bounds__(256) void k_part(const int* __restrict__ ei,
                                                     const int* __restrict__ et,
                                                     int* __restrict__ gcur,
                                                     unsigned long long* __restrict__ part) {
    __shared__ unsigned long long stage[PTILE];     // 32 KB
    __shared__ int hist[NBUCK];                     // 2 KB
    __shared__ int lofs[NBUCK];
    __shared__ int lbase[NBUCK];
    __shared__ int sscan[256];
    int t = threadIdx.x;
    int e0 = blockIdx.x * PTILE;
    int tile_n = N_EDGES - e0; if (tile_n > PTILE) tile_n = PTILE;

    for (int k = t; k < NBUCK; k += 256) hist[k] = 0;
    __syncthreads();
    // pass A: load 16 edges/thread; hist atomic returns rank (kept in meta)
    int src[16], meta[16];
#pragma unroll
    for (int j = 0; j < 16; j++) {
        int e = e0 + j * 256 + t;
        if (e < N_EDGES) {
            int s = ei[e];
            int d = ei[N_EDGES + e];
            int r = et[e];
            int bb = d / BNODE;                     // magic-mul const div
            int lk = (d - bb * BNODE) * 5 + r;
            int rank = atomicAdd(&hist[bb], 1);     // rank < 4096
            src[j] = s; meta[j] = (bb << 22) | (rank << 10) | lk;
        } else meta[j] = -1;
    }
    __syncthreads();
    // exclusive scan over 511 buckets: thread t owns slots 2t, 2t+1
    int h0 = (2 * t     < NBUCK) ? hist[2 * t]     : 0;
    int h1 = (2 * t + 1 < NBUCK) ? hist[2 * t + 1] : 0;
    int s2 = h0 + h1;
    sscan[t] = s2;
    __syncthreads();
    for (int off = 1; off < 256; off <<= 1) {
        int xv = (t >= off) ? sscan[t - off] : 0;
        __syncthreads();
        sscan[t] += xv;
        __syncthreads();
    }
    int excl = sscan[t] - s2;
    if (2 * t     < NBUCK) lofs[2 * t]     = excl;
    if (2 * t + 1 < NBUCK) lofs[2 * t + 1] = excl + h0;
    // reserve global space per bucket
    for (int k = t; k < NBUCK; k += 256) lbase[k] = atomicAdd(&gcur[k], hist[k]);
    __syncthreads();
    // pass B: place records at lofs[bb]+rank — NO atomics
#pragma unroll
    for (int j = 0; j < 16; j++) {
        if (meta[j] >= 0) {
            int lk   = meta[j] & 1023;
            int rank = (meta[j] >> 10) & 4095;
            int bb   = ((unsigned)meta[j]) >> 22;
            stage[lofs[bb] + rank] =
                ((unsigned long long)(unsigned)((bb << 16) | lk) << 32)
                | (unsigned)src[j];
        }
    }
    __syncthreads();
    // pass C: sequential copy-out — per-bucket runs land coalesced
    for (int i = t; i < tile_n; i += 256) {
        unsigned long long u = stage[i];
        unsigned hi = (unsigned)(u >> 32);
        int bb = hi >> 16;
        unsigned long long lk = hi & 0xFFFFu;
        int pos = lbase[bb] + (i - lofs[bb]);
        if (pos < BCAP)
            part[(size_t)bb * BCAP + pos] = (lk << 32) | (u & 0xffffffffULL);
    }
}

// ---------------- CSR pass 2: per-bucket sort, DIRECT global scatter ----------------
// Single LDS-atomic pass (rank from atomicAdd return, kept in registers) and
// direct fire-and-forget stores into the block's contiguous srcs window — no
// 42 KB lsrc staging, no copy-out, no cursor reset. LDS 8.9 KB. Pad slots and
// scattered slots are disjoint -> no store-order hazard.
static __global__ __launch_bounds__(1024) void k_bsort(const unsigned long long* __restrict__ part,
                                                       const int* __restrict__ gcur,
                                                       int* __restrict__ offs,
                                                       int* __restrict__ cnt,
                                                       int* __restrict__ srcs) {
    __shared__ int lhist[NKEY];      // 3.9 KB
    __shared__ int lscan[NKEY];      // 3.9 KB
    __shared__ int sscan[256];       // 1 KB
    int b = blockIdx.x;
    int t = threadIdx.x;
    int n = gcur[b]; if (n > BCAP) n = BCAP;
    const unsigned long long* reg = part + (size_t)b * BCAP;

    for (int k = t; k < NKEY; k += 1024) lhist[k] = 0;
    __syncthreads();
    // read + histogram; atomic returns rank. kr packs rank(13b)|key(10b).
    int kr[7], sr[7];
#pragma unroll
    for (int j = 0; j < 7; j++) {
        int i = j * 1024 + t;                       // 7*1024 = BCAP
        if (i < n) {
            unsigned long long u = reg[i];
            int k = (int)(u >> 32);
            int rank = atomicAdd(&lhist[k], 1);
            kr[j] = (rank << 10) | k;
            sr[j] = (int)(u & 0xffffffffULL);
        } else kr[j] = -1;
    }
    __syncthreads();

    // exclusive scan over PADDED counts (980 = 196 threads x 5 keys)
    int loc[5]; int s5 = 0;
    if (t < 196) {
#pragma unroll
        for (int j = 0; j < 5; j++) { loc[j] = s5; s5 += (lhist[t * 5 + j] + 7) & ~7; }
    }
    if (t < 256) sscan[t] = (t < 196) ? s5 : 0;
    __syncthreads();
    for (int off = 1; off < 256; off <<= 1) {
        int x = (t >= off && t < 256) ? sscan[t - off] : 0;
        __syncthreads();
        if (t < 256) sscan[t] += x;
        __syncthreads();
    }
    if (t < 196) {
        int excl = sscan[t] - s5;
#pragma unroll
        for (int j = 0; j < 5; j++) lscan[t * 5 + j] = excl + loc[j];
    }
    __syncthreads();
    int ptot = sscan[255]; if (ptot > PBCAP) ptot = PBCAP;
    int base = b * PBCAP;

    if (t < 196) {
#pragma unroll
        for (int j = 0; j < 5; j++) {
            int k = t * 5 + j;
            int segid = b * NKEY + k;               // = (b*196+t)*5 + j
            if (segid < SEG) {
                cnt[segid]  = lhist[k];
                offs[segid] = base + lscan[k];
            }
        }
    }
    // pad-slot DUMMY fill (slots [cr, pr) of each run) — disjoint from scatter
    if (t < 196) {
#pragma unroll
        for (int j = 0; j < 5; j++) {
            int k = t * 5 + j;
            int cr = lhist[k];
            int st = lscan[k] + cr;
            int en = lscan[k] + ((cr + 7) & ~7);
            for (int i = st; i < en; i++)
                if (i < PBCAP) srcs[base + i] = DUMMY;
        }
    }
    if (t < 16) {                                   // +16 tail for prefetch slack
        int i = ptot + t;
        if (i < PBCAP) srcs[base + i] = DUMMY;
    }
    // direct scatter: pos = lscan[key] + rank — no atomics, no staging
#pragma unroll
    for (int j = 0; j < 7; j++) {
        if (kr[j] >= 0) {
            int k    = kr[j] & 1023;
            int rank = ((unsigned)kr[j]) >> 10;
            int pos  = lscan[k] + rank;
            if (pos < PBCAP) srcs[base + pos] = sr[j];
        }
    }
}

// ---------------- merged prep: fp16 table/pad + RGCN B-frags + MLP B-frags -------
// blockIdx < 12501: table/pad body; < 12597: RGCN B-frags; < 12725: MLP B-frags.
static __global__ __launch_bounds__(256) void k_prep(
    const float* __restrict__ x,
    __half* __restrict__ ht0, __half* __restrict__ ht1, __half* __restrict__ ht2,
    __half* __restrict__ ht3, __half* __restrict__ ht4, int* __restrict__ srcs,
    const float* __restrict__ ba0, const float* __restrict__ co0, const float* __restrict__ ro0,
    const float* __restrict__ ba1, const float* __restrict__ co1, const float* __restrict__ ro1,
    const float* __restrict__ ba2, const float* __restrict__ co2, const float* __restrict__ ro2,
    const float* __restrict__ ba3, const float* __restrict__ co3, const float* __restrict__ ro3,
    __half* __restrict__ Wb, const float* __restrict__ w1, __half* __restrict__ Wm) {
    int blk = blockIdx.x;
    int t = threadIdx.x;
    if (blk < 12501) {
        // ---- fp16 layer-0 table + dummy rows + srcs slack ----
        int tid = blk * 256 + t;
        if (tid < (N_NODES + 1) * 32) {
            int nd = tid >> 5, ii = tid & 31;
            float v = (nd < N_NODES && ii < 4) ? x[(nd << 2) + ii] : 0.f;
            ht0[tid] = __float2half(v);
        } else {
            int r = tid - (N_NODES + 1) * 32;
            if (r < 128) {
                __half* hp = (r < 32) ? ht1 : (r < 64) ? ht2 : (r < 96) ? ht3 : ht4;
                hp[N_NODES * 32 + (r & 31)] = __float2half(0.f);   // dummy rows
            } else if (r < 144) srcs[NBUCK * PBCAP + (r - 128)] = DUMMY;  // slack
        }
    } else if (blk < 12501 + 96) {
        // ---- RGCN fp16 B-fragments, K=192, comp folded (24576 threads) ----
        int idx = (blk - 12501) * 256 + t;
        int j    = idx & 7;
        int lane = (idx >> 3) & 63;
        int tile = (idx >> 9) & 1;
        int ls   = idx >> 10;                       // l*6 + s, < 24
        int l    = ls / 6;
        int s    = ls - l * 6;
        const float* basis = (l == 0) ? ba0 : (l == 1) ? ba1 : (l == 2) ? ba2 : ba3;
        const float* comp  = (l == 0) ? co0 : (l == 1) ? co1 : (l == 2) ? co2 : co3;
        const float* root  = (l == 0) ? ro0 : (l == 1) ? ro1 : (l == 2) ? ro2 : ro3;
        int in_c = (l == 0) ? 4 : HID;
        int d = ((lane >> 4) << 3) + j;             // dim within slot, 0..31
        int o = tile * 16 + (lane & 15);
        float v = 0.f;
        if (d < in_c) {
            if (s < 5) {
                float acc = 0.f;
#pragma unroll
                for (int b = 0; b < N_BASES; b++)
                    acc += comp[s * N_BASES + b] * basis[(b * in_c + d) * HID + o];
                v = acc;
            } else {
                v = root[d * HID + o];
            }
        }
        Wb[idx] = __float2half(v);
    } else {
        // ---- w1 [256x128] fp16 B-fragments (32768 threads) ----
        int idx = (blk - 12597) * 256 + t;
        int j    = idx & 7;
        int lane = (idx >> 3) & 63;
        int s    = (idx >> 9) & 7;
        int tile = idx >> 12;                       // < 8
        int k = s * 32 + ((lane >> 4) << 3) + j;
        int o = tile * 16 + (lane & 15);
        Wm[idx] = __float2half(w1[k * 128 + o]);
    }
}

// ---------------- fused RGCN layer (frozen from R2) ----------------
// 32 nodes / 128 threads per block. Phase 1: 4 lanes = 1 node, dwordx4 gathers;
// all 5 relations' edge-list int4 loads pre-issued. Raw per-relation fp16 means
// -> sAgg (K=192); comp pre-folded into Wb.
// Phase 2: [16x192]x[192x32] per wave via 6x2 mfma_f32_16x16x32_f16.
static __global__ __launch_bounds__(128, 5) void k_layer(
    const __half* __restrict__ tab, const int* __restrict__ offs,
    const int* __restrict__ cnt, const int* __restrict__ srcs,
    const __half* __restrict__ Wbl, const float* __restrict__ bias,
    __half* __restrict__ hout) {
    __shared__ __align__(16) __half sAgg[32 * ASTR];   // 13.3 KB
    int t = threadIdx.x;
    int wave = t >> 6, lane = t & 63;
    int nsub = lane >> 2, cp = lane & 3;               // node-in-wave, 16B chunk
    int nl = wave * 16 + nsub;                         // LDS row 0..31
    int n = blockIdx.x * 32 + nl;                      // exact: 3125*32 = 100000
    const half8* tab8 = (const half8*)tab;

    int s5 = n * N_REL;
    int o0 = offs[s5];
    int cc[5];
#pragma unroll
    for (int r = 0; r < 5; r++) cc[r] = cnt[s5 + r];

    __half* row = sAgg + nl * ASTR;
    // self slot (k = 160..191) — independent load, issued early
    *(half8*)(row + 160 + cp * 8) = tab8[n * 4 + cp];

    // pre-compute run starts, pre-issue ALL edge-list loads (10 outstanding)
    int ob[5];
    {
        int orun = o0;
#pragma unroll
        for (int r = 0; r < 5; r++) { ob[r] = orun; orun += (cc[r] + 7) & ~7; }
    }
    int4 E0[5], E1[5];
#pragma unroll
    for (int r = 0; r < 5; r++) {
        const int* sp = srcs + ob[r];                  // 32B-aligned run start
        E0[r] = *(const int4*)(sp);
        E1[r] = *(const int4*)(sp + 4);
    }
#pragma unroll
    for (int r = 0; r < 5; r++) {
        int cr = cc[r];
        int pr = (cr + 7) & ~7;
        const int* sp = srcs + ob[r];
        half8 g0 = tab8[E0[r].x * 4 + cp], g1 = tab8[E0[r].y * 4 + cp];
        half8 g2 = tab8[E0[r].z * 4 + cp], g3 = tab8[E0[r].w * 4 + cp];
        half8 g4 = tab8[E1[r].x * 4 + cp], g5 = tab8[E1[r].y * 4 + cp];
        half8 g6 = tab8[E1[r].z * 4 + cp], g7 = tab8[E1[r].w * 4 + cp];
        half8 sb = ((g0 + g1) + (g2 + g3)) + ((g4 + g5) + (g6 + g7));
        float S0 = (float)sb[0], S1 = (float)sb[1], S2 = (float)sb[2], S3 = (float)sb[3];
        float S4 = (float)sb[4], S5 = (float)sb[5], S6 = (float)sb[6], S7 = (float)sb[7];
        for (int s8 = 8; s8 < pr; s8 += 8) {           // residual batches (~20%)
            int4 f0 = *(const int4*)(sp + s8);
            int4 f1 = *(const int4*)(sp + s8 + 4);
            half8 h0 = tab8[f0.x * 4 + cp], h1 = tab8[f0.y * 4 + cp];
            half8 h2 = tab8[f0.z * 4 + cp], h3 = tab8[f0.w * 4 + cp];
            half8 h4 = tab8[f1.x * 4 + cp], h5 = tab8[f1.y * 4 + cp];
            half8 h6 = tab8[f1.z * 4 + cp], h7 = tab8[f1.w * 4 + cp];
            half8 rb = ((h0 + h1) + (h2 + h3)) + ((h4 + h5) + (h6 + h7));
            S0 += (float)rb[0]; S1 += (float)rb[1]; S2 += (float)rb[2]; S3 += (float)rb[3];
            S4 += (float)rb[4]; S5 += (float)rb[5]; S6 += (float)rb[6]; S7 += (float)rb[7];
        }
        float ic = (cr > 0) ? __builtin_amdgcn_rcpf((float)cr) : 0.f;
        half8 u;
        u[0] = (_Float16)(S0 * ic); u[1] = (_Float16)(S1 * ic);
        u[2] = (_Float16)(S2 * ic); u[3] = (_Float16)(S3 * ic);
        u[4] = (_Float16)(S4 * ic); u[5] = (_Float16)(S5 * ic);
        u[6] = (_Float16)(S6 * ic); u[7] = (_Float16)(S7 * ic);
        *(half8*)(row + r * 32 + cp * 8) = u;          // slot r: k = r*32..r*32+31
    }
    __syncthreads();

    // phase 2: wave w owns rows w*16..w*16+15, both 16-col tiles
    floatx4 acc0 = {0.f, 0.f, 0.f, 0.f}, acc1 = {0.f, 0.f, 0.f, 0.f};
    const __half* aBase = sAgg + (wave * 16 + (lane & 15)) * ASTR + ((lane >> 4) << 3);
    const __half* bBase = Wbl + lane * 8;
#pragma unroll
    for (int s = 0; s < 6; s++) {
        half8 a  = *(const half8*)(aBase + s * 32);
        half8 f0 = *(const half8*)(bBase + (s * 2 + 0) * 512);
        half8 f1 = *(const half8*)(bBase + (s * 2 + 1) * 512);
        acc0 = __builtin_amdgcn_mfma_f32_16x16x32_f16(a, f0, acc0, 0, 0, 0);
        acc1 = __builtin_amdgcn_mfma_f32_16x16x32_f16(a, f1, acc1, 0, 0, 0);
    }
    int oc = lane & 15;
    float bi0 = bias[oc], bi1 = bias[16 + oc];
#pragma unroll
    for (int r = 0; r < 4; r++) {
        int node = blockIdx.x * 32 + wave * 16 + ((lane >> 4) << 2) + r;
        hout[node * 32 + oc]      = __float2half(tanhf(acc0[r] + bi0));
        hout[node * 32 + 16 + oc] = __float2half(tanhf(acc1[r] + bi1));
    }
}

// ---------------- final MLP via MFMA: 16 graphs/block ----------------
static __global__ __launch_bounds__(256) void k_mlp(
    const __half* __restrict__ h1, const __half* __restrict__ h2,
    const __half* __restrict__ h3, const __half* __restrict__ h4,
    const int* __restrict__ uidx, const int* __restrict__ iidx,
    const __half* __restrict__ Wm, const float* __restrict__ b1,
    const float* __restrict__ w2, const float* __restrict__ b2,
    float* __restrict__ out) {
    __shared__ __align__(16) __half sg[16 * 264];   // 8.25 KB
    __shared__ float sacc[4][16];
    int t = threadIdx.x, wave = t >> 6, lane = t & 63;
    int g0 = blockIdx.x * 16;
    int lt = lane >> 4, lp = lane & 15;
    const __half* htab = (lt == 0) ? h1 : (lt == 1) ? h2 : (lt == 2) ? h3 : h4;
#pragma unroll
    for (int gg2 = 0; gg2 < 4; gg2++) {
        int gg = wave * 4 + gg2;
        int g = g0 + gg;
        int u = uidx[g], it = iidx[g];
        __half2* dst = (__half2*)(sg + gg * 264);
        dst[lt * 16 + lp]      = ((const __half2*)(htab + u * 32))[lp];
        dst[64 + lt * 16 + lp] = ((const __half2*)(htab + it * 32))[lp];
    }
    __syncthreads();
    floatx4 acc0 = {0.f, 0.f, 0.f, 0.f}, acc1 = {0.f, 0.f, 0.f, 0.f};
    const __half* aBase = sg + (lane & 15) * 264 + ((lane >> 4) << 3);
    const __half* bB0 = Wm + (wave * 2 + 0) * 4096 + lane * 8;
    const __half* bB1 = Wm + (wave * 2 + 1) * 4096 + lane * 8;
#pragma unroll
    for (int s = 0; s < 8; s++) {
        half8 a  = *(const half8*)(aBase + s * 32);
        half8 f0 = *(const half8*)(bB0 + s * 512);
        half8 f1 = *(const half8*)(bB1 + s * 512);
        acc0 = __builtin_amdgcn_mfma_f32_16x16x32_f16(a, f0, acc0, 0, 0, 0);
        acc1 = __builtin_amdgcn_mfma_f32_16x16x32_f16(a, f1, acc1, 0, 0, 0);
    }
    int o0 = wave * 32 + (lane & 15);
    int o1 = o0 + 16;
    float b10 = b1[o0], b11 = b1[o1], w20 = w2[o0], w21 = w2[o1];
#pragma unroll
    for (int r = 0; r < 4; r++) {
        float z0 = fmaxf(acc0[r] + b10, 0.f);
        float z1 = fmaxf(acc1[r] + b11, 0.f);
        float v = z0 * w20 + z1 * w21;
#pragma unroll
        for (int off = 1; off < 16; off <<= 1) v += __shfl_xor(v, off);
        if ((lane & 15) == 0) sacc[wave][((lane >> 4) << 2) + r] = v;
    }
    __syncthreads();
    if (t < 16)
        out[g0 + t] = sacc[0][t] + sacc[1][t] + sacc[2][t] + sacc[3][t] + b2[0];
}

// ---------------- launcher ----------------
extern "C" void kernel_launch(void* const* d_in, const int* in_sizes, int n_in,
                              void* d_out, int out_size, void* d_ws, size_t ws_size,
                              hipStream_t stream) {
    const float* x  = (const float*)d_in[0];
    const int*   ei = (const int*)d_in[1];
    const int*   et = (const int*)d_in[2];
    const int*   ui = (const int*)d_in[3];
    const int*   ii = (const int*)d_in[4];
    const float* w1 = (const float*)d_in[21];
    const float* b1 = (const float*)d_in[22];
    const float* w2 = (const float*)d_in[23];
    const float* b2 = (const float*)d_in[24];

    // workspace layout (bytes, 128-aligned).
    char* ws = (char*)d_ws;
    if (ws_size < 92167680UL) return;
    int*    gcur = (int*)(ws + 0);              // [511]
    int*    offs = (int*)(ws + 2048);           // [500000]
    int*    cnt  = (int*)(ws + 2002176);        // [500000]
    int*    srcs = (int*)(ws + 4002304);        // [511*10752] + 16 slack, ends ~25.98MB
    __half* Wb   = (__half*)(ws + 26079488);    // [24576] fp16 RGCN B-frags (K=192)
    __half* Wm   = (__half*)(ws + 26128640);    // [32768] fp16 MLP B-frags
    __half* ht0  = (__half*)(ws + 26194176);    // [100001*32] fp16 dense
    __half* ht1  = (__half*)(ws + 32594304);    // [100001*32]
    __half* ht2  = (__half*)(ws + 38994432);    // [100001*32]
    __half* ht3  = (__half*)(ws + 45394560);    // [100001*32]
    __half* ht4  = (__half*)(ws + 51794688);    // [100001*32], ends ~58.2MB
    // part aliases ht1.. tail (dead after k_bsort; layers run later): 511*7168*8 = 29.3MB
    unsigned long long* part = (unsigned long long*)(ws + 32594304);  // ends ~61.9MB

    hipMemsetAsync(gcur, 0, NBUCK * 4, stream);

    k_part<<<(N_EDGES + PTILE - 1) / PTILE, 256, 0, stream>>>(ei, et, gcur, part);
    k_bsort<<<NBUCK, 1024, 0, stream>>>(part, gcur, offs, cnt, srcs);
    k_prep<<<12725, 256, 0, stream>>>(          // 12501 pad + 96 wprepB + 128 wprepM
        x, ht0, ht1, ht2, ht3, ht4, srcs,
        (const float*)d_in[5],  (const float*)d_in[6],  (const float*)d_in[7],
        (const float*)d_in[9],  (const float*)d_in[10], (const float*)d_in[11],
        (const float*)d_in[13], (const float*)d_in[14], (const float*)d_in[15],
        (const float*)d_in[17], (const float*)d_in[18], (const float*)d_in[19],
        Wb, w1, Wm);

    __half* tabs[5] = {ht0, ht1, ht2, ht3, ht4};
    for (int l = 0; l < 4; l++) {
        const float* bias = (const float*)d_in[8 + 4 * l];
        k_layer<<<N_NODES / 32, 128, 0, stream>>>(
            tabs[l], offs, cnt, srcs, Wb + l * 6144, bias, tabs[l + 1]);
    }
    k_mlp<<<256, 256, 0, stream>>>(ht1, ht2, ht3, ht4, ui, ii, Wm, b1, w2, b2,
                                   (float*)d_out);
}

// Round 6
// 347.277 us; speedup vs baseline: 1.0306x; 1.0306x over previous
//
#include <hip/hip_runtime.h>
#include <hip/hip_bf16.h>
#include <hip/hip_fp16.h>

#define N_NODES 100000
#define N_EDGES 3200000
#define N_GRAPHS 4096
#define N_REL 5
#define N_BASES 4
#define HID 32
#define SEG (N_NODES*N_REL)
#define DUMMY N_NODES            // extra node whose feature row is all-zero

#define BNODE 196                // dst nodes per bucket
#define NBUCK 511                // ceil(100000/196)
#define BCAP  7168               // part-record capacity per bucket (mean 6272)
#define PBCAP 10752              // padded srcs capacity per bucket (mean ~9.4K)
#define NKEY  980                // 196 nodes * 5 rels
#define PTILE 4096               // edges per k_part block

#define KDIM 192                 // MFMA K: 5 rel means * 32 + 32 self
#define ASTR 208                 // sAgg row stride in halves (416 B: 16B-aligned)

typedef _Float16 half8 __attribute__((ext_vector_type(8)));
typedef _Float16 half4 __attribute__((ext_vector_type(4)));
typedef float floatx4 __attribute__((ext_vector_type(4)));

__device__ inline half4 qshfl_xor(half4 v, int m) {
    union U { half4 h; long long l; } u; u.h = v;
    u.l = __shfl_xor(u.l, m);
    return u.h;
}
__device__ inline int qsel(int cp, int4 v) {
    int a = (cp & 1) ? v.y : v.x;
    int b = (cp & 1) ? v.w : v.z;
    return (cp & 2) ? b : a;
}

// ---------------- CSR pass 1 (R4-proven): partition edges into dst-range buckets ----
static __global__ __launch_bounds__(256) void k_part(const int* __restrict__ ei,
                                                     const int* __restrict__ et,
                                                     int* __restrict__ gcur,
                                                     unsigned long long* __restrict__ part) {
    __shared__ unsigned long long stage[PTILE];     // 32 KB
    __shared__ int hist[NBUCK];                     // 2 KB
    __shared__ int lofs[NBUCK];
    __shared__ int lbase[NBUCK];
    __shared__ int sscan[256];
    int t = threadIdx.x;
    int e0 = blockIdx.x * PTILE;
    int tile_n = N_EDGES - e0; if (tile_n > PTILE) tile_n = PTILE;

    for (int k = t; k < NBUCK; k += 256) hist[k] = 0;
    __syncthreads();
    int src[16], bkt[16], lkey[16];
#pragma unroll
    for (int j = 0; j < 16; j++) {
        int e = e0 + j * 256 + t;
        if (e < N_EDGES) {
            int s = ei[e];
            int d = ei[N_EDGES + e];
            int r = et[e];
            int bb = d / BNODE;                     // magic-mul const div
            src[j] = s; bkt[j] = bb; lkey[j] = (d - bb * BNODE) * 5 + r;
            atomicAdd(&hist[bb], 1);
        } else bkt[j] = -1;
    }
    __syncthreads();
    int h0 = (2 * t     < NBUCK) ? hist[2 * t]     : 0;
    int h1 = (2 * t + 1 < NBUCK) ? hist[2 * t + 1] : 0;
    int s2 = h0 + h1;
    sscan[t] = s2;
    __syncthreads();
    for (int off = 1; off < 256; off <<= 1) {
        int xv = (t >= off) ? sscan[t - off] : 0;
        __syncthreads();
        sscan[t] += xv;
        __syncthreads();
    }
    int excl = sscan[t] - s2;
    if (2 * t     < NBUCK) lofs[2 * t]     = excl;
    if (2 * t + 1 < NBUCK) lofs[2 * t + 1] = excl + h0;
    for (int k = t; k < NBUCK; k += 256) lbase[k] = atomicAdd(&gcur[k], hist[k]);
    __syncthreads();
    for (int k = t; k < NBUCK; k += 256) hist[k] = 0;   // reuse as cursor
    __syncthreads();
#pragma unroll
    for (int j = 0; j < 16; j++) {
        if (bkt[j] >= 0) {
            int rank = atomicAdd(&hist[bkt[j]], 1);
            stage[lofs[bkt[j]] + rank] =
                ((unsigned long long)(unsigned)((bkt[j] << 16) | lkey[j]) << 32)
                | (unsigned)src[j];
        }
    }
    __syncthreads();
    for (int i = t; i < tile_n; i += 256) {
        unsigned long long u = stage[i];
        unsigned hi = (unsigned)(u >> 32);
        int bb = hi >> 16;
        unsigned long long lk = hi & 0xFFFFu;
        int pos = lbase[bb] + (i - lofs[bb]);
        if (pos < BCAP)
            part[(size_t)bb * BCAP + pos] = (lk << 32) | (u & 0xffffffffULL);
    }
}

// ---------------- CSR pass 2 (R4-proven): per-bucket sort, LDS-staged copy-out ----
static __global__ __launch_bounds__(1024) void k_bsort(const unsigned long long* __restrict__ part,
                                                       const int* __restrict__ gcur,
                                                       int* __restrict__ offs,
                                                       int* __restrict__ cnt,
                                                       int* __restrict__ srcs) {
    __shared__ int lhist[NKEY];      // 3.9 KB
    __shared__ int lscan[NKEY];      // 3.9 KB
    __shared__ int sscan[256];       // 1 KB
    __shared__ int lsrc[PBCAP];      // 42 KB
    int b = blockIdx.x;
    int t = threadIdx.x;
    int n = gcur[b]; if (n > BCAP) n = BCAP;
    const unsigned long long* reg = part + (size_t)b * BCAP;

    for (int k = t; k < NKEY; k += 1024) lhist[k] = 0;
    __syncthreads();
    for (int i = t; i < n; i += 1024)
        atomicAdd(&lhist[(int)(reg[i] >> 32)], 1);
    __syncthreads();

    int loc[5]; int s5 = 0;
    if (t < 196) {
#pragma unroll
        for (int j = 0; j < 5; j++) { loc[j] = s5; s5 += (lhist[t * 5 + j] + 7) & ~7; }
    }
    if (t < 256) sscan[t] = (t < 196) ? s5 : 0;
    __syncthreads();
    for (int off = 1; off < 256; off <<= 1) {
        int x = (t >= off && t < 256) ? sscan[t - off] : 0;
        __syncthreads();
        if (t < 256) sscan[t] += x;
        __syncthreads();
    }
    if (t < 196) {
        int excl = sscan[t] - s5;
#pragma unroll
        for (int j = 0; j < 5; j++) lscan[t * 5 + j] = excl + loc[j];
    }
    __syncthreads();
    int ptot = sscan[255]; if (ptot > PBCAP) ptot = PBCAP;
    int pout = ptot + 16; if (pout > PBCAP) pout = PBCAP;

    int base = b * PBCAP;
    if (t < 196) {
#pragma unroll
        for (int j = 0; j < 5; j++) {
            int k = t * 5 + j;
            int segid = b * NKEY + k;               // = (b*196+t)*5 + j
            if (segid < SEG) {
                cnt[segid]  = lhist[k];
                offs[segid] = base + lscan[k];
            }
        }
    }
    __syncthreads();
    for (int k = t; k < NKEY; k += 1024) lhist[k] = 0;
    for (int i = t; i < pout; i += 1024) lsrc[i] = DUMMY;
    __syncthreads();
    for (int i = t; i < n; i += 1024) {
        unsigned long long u = reg[i];
        int k = (int)(u >> 32);
        int pos = lscan[k] + atomicAdd(&lhist[k], 1);
        if (pos < PBCAP) lsrc[pos] = (int)(u & 0xffffffffULL);
    }
    __syncthreads();
    for (int i = t; i < pout; i += 1024) srcs[base + i] = lsrc[i];
}

// ---------------- merged prep: compact xt table + pads + B-frags ----------------
// blk < 1563: xt [N+1][4] fp16; blk == 1563: dummy rows ht1..4 + srcs slack;
// blk in [1564,1660): RGCN B-frags; blk in [1660,1788): MLP B-frags.
static __global__ __launch_bounds__(256) void k_prep(
    const float* __restrict__ x, __half* __restrict__ xt,
    __half* __restrict__ ht1, __half* __restrict__ ht2,
    __half* __restrict__ ht3, __half* __restrict__ ht4, int* __restrict__ srcs,
    const float* __restrict__ ba0, const float* __restrict__ co0, const float* __restrict__ ro0,
    const float* __restrict__ ba1, const float* __restrict__ co1, const float* __restrict__ ro1,
    const float* __restrict__ ba2, const float* __restrict__ co2, const float* __restrict__ ro2,
    const float* __restrict__ ba3, const float* __restrict__ co3, const float* __restrict__ ro3,
    __half* __restrict__ Wb, const float* __restrict__ w1, __half* __restrict__ Wm) {
    int blk = blockIdx.x;
    int t = threadIdx.x;
    if (blk < 1563) {
        int tid = blk * 256 + t;                    // < (N+1)*4 = 400004
        if (tid < (N_NODES + 1) * 4) {
            float v = (tid < N_NODES * 4) ? x[tid] : 0.f;
            xt[tid] = __float2half(v);
        }
    } else if (blk == 1563) {
        if (t < 128) {
            __half* hp = (t < 32) ? ht1 : (t < 64) ? ht2 : (t < 96) ? ht3 : ht4;
            hp[N_NODES * 32 + (t & 31)] = __float2half(0.f);   // dummy rows
        } else if (t < 144) srcs[NBUCK * PBCAP + (t - 128)] = DUMMY;  // slack
    } else if (blk < 1564 + 96) {
        // ---- RGCN fp16 B-fragments, K=192, comp folded (24576 threads) ----
        int idx = (blk - 1564) * 256 + t;
        int j    = idx & 7;
        int lane = (idx >> 3) & 63;
        int tile = (idx >> 9) & 1;
        int ls   = idx >> 10;                       // l*6 + s, < 24
        int l    = ls / 6;
        int s    = ls - l * 6;
        const float* basis = (l == 0) ? ba0 : (l == 1) ? ba1 : (l == 2) ? ba2 : ba3;
        const float* comp  = (l == 0) ? co0 : (l == 1) ? co1 : (l == 2) ? co2 : co3;
        const float* root  = (l == 0) ? ro0 : (l == 1) ? ro1 : (l == 2) ? ro2 : ro3;
        int in_c = (l == 0) ? 4 : HID;
        int d = ((lane >> 4) << 3) + j;             // dim within slot, 0..31
        int o = tile * 16 + (lane & 15);
        float v = 0.f;
        if (d < in_c) {
            if (s < 5) {
                float acc = 0.f;
#pragma unroll
                for (int b = 0; b < N_BASES; b++)
                    acc += comp[s * N_BASES + b] * basis[(b * in_c + d) * HID + o];
                v = acc;
            } else {
                v = root[d * HID + o];
            }
        }
        Wb[idx] = __float2half(v);
    } else {
        // ---- w1 [256x128] fp16 B-fragments (32768 threads) ----
        int idx = (blk - 1660) * 256 + t;
        int j    = idx & 7;
        int lane = (idx >> 3) & 63;
        int s    = (idx >> 9) & 7;
        int tile = idx >> 12;                       // < 8
        int k = s * 32 + ((lane >> 4) << 3) + j;
        int o = tile * 16 + (lane & 15);
        Wm[idx] = __float2half(w1[k * 128 + o]);
    }
}

// ---------------- RGCN layer 0: compact 8B-row gathers from L2-resident xt ------
// 1-wave blocks (16 nodes): 6.7 KB LDS -> 24 blocks/CU (LDS-capped, 159.7/160KB).
// Per batch of 8 edges, lane cp loads 2 half4 rows; quad shfl-reduce (same
// depth-3 fp16 tree as main path) -> fp32 across batches. Only dims 0..3 of each
// K-slot are written; the rest are zeroed once (Wb's layer-0 weights are 0 there).
static __global__ __launch_bounds__(64, 6) void k_layer0(
    const __half* __restrict__ xt, const int* __restrict__ offs,
    const int* __restrict__ cnt, const int* __restrict__ srcs,
    const __half* __restrict__ Wbl, const float* __restrict__ bias,
    __half* __restrict__ hout) {
    __shared__ __align__(16) __half sAgg[16 * ASTR];   // 6656 B
    int lane = threadIdx.x;
    int nsub = lane >> 2, cp = lane & 3;
    int n = blockIdx.x * 16 + nsub;                    // 6250*16 = 100000
    const half4* xt4 = (const half4*)xt;

    half8 z = {};
    for (int i = lane; i < 16 * ASTR / 8; i += 64) ((half8*)sAgg)[i] = z;

    int s5 = n * N_REL;
    int o0 = offs[s5];
    int cc[5];
#pragma unroll
    for (int r = 0; r < 5; r++) cc[r] = cnt[s5 + r];
    int ob[5];
    {
        int orun = o0;
#pragma unroll
        for (int r = 0; r < 5; r++) { ob[r] = orun; orun += (cc[r] + 7) & ~7; }
    }
    int4 E0[5], E1[5];
#pragma unroll
    for (int r = 0; r < 5; r++) {
        const int* sp = srcs + ob[r];
        E0[r] = *(const int4*)(sp);
        E1[r] = *(const int4*)(sp + 4);
    }
    half4 selfv = xt4[n];
    __syncthreads();                                   // zero-fill visible

    __half* row = sAgg + nsub * ASTR;
    if (cp == 0) *(half4*)(row + 160) = selfv;         // self slot, dims 0..3

#pragma unroll
    for (int r = 0; r < 5; r++) {
        int cr = cc[r];
        int pr = (cr + 7) & ~7;
        const int* sp = srcs + ob[r];
        half4 xa = xt4[qsel(cp, E0[r])];
        half4 xb = xt4[qsel(cp, E1[r])];
        half4 hs = xa + xb;
        hs += qshfl_xor(hs, 1);
        hs += qshfl_xor(hs, 2);
        float S0 = (float)hs[0], S1 = (float)hs[1], S2 = (float)hs[2], S3 = (float)hs[3];
        for (int s8 = 8; s8 < pr; s8 += 8) {
            int4 f0 = *(const int4*)(sp + s8);
            int4 f1 = *(const int4*)(sp + s8 + 4);
            half4 ya = xt4[qsel(cp, f0)];
            half4 yb = xt4[qsel(cp, f1)];
            half4 rs = ya + yb;
            rs += qshfl_xor(rs, 1);
            rs += qshfl_xor(rs, 2);
            S0 += (float)rs[0]; S1 += (float)rs[1]; S2 += (float)rs[2]; S3 += (float)rs[3];
        }
        float ic = (cr > 0) ? __builtin_amdgcn_rcpf((float)cr) : 0.f;
        if (cp == 0) {
            half4 u;
            u[0] = (_Float16)(S0 * ic); u[1] = (_Float16)(S1 * ic);
            u[2] = (_Float16)(S2 * ic); u[3] = (_Float16)(S3 * ic);
            *(half4*)(row + r * 32) = u;               // slot r, dims 0..3
        }
    }
    __syncthreads();

    floatx4 acc0 = {0.f, 0.f, 0.f, 0.f}, acc1 = {0.f, 0.f, 0.f, 0.f};
    const __half* aBase = sAgg + (lane & 15) * ASTR + ((lane >> 4) << 3);
    const __half* bBase = Wbl + lane * 8;
#pragma unroll
    for (int s = 0; s < 6; s++) {
        half8 a  = *(const half8*)(aBase + s * 32);
        half8 f0 = *(const half8*)(bBase + (s * 2 + 0) * 512);
        half8 f1 = *(const half8*)(bBase + (s * 2 + 1) * 512);
        acc0 = __builtin_amdgcn_mfma_f32_16x16x32_f16(a, f0, acc0, 0, 0, 0);
        acc1 = __builtin_amdgcn_mfma_f32_16x16x32_f16(a, f1, acc1, 0, 0, 0);
    }
    int oc = lane & 15;
    float bi0 = bias[oc], bi1 = bias[16 + oc];
#pragma unroll
    for (int r = 0; r < 4; r++) {
        int node = blockIdx.x * 16 + ((lane >> 4) << 2) + r;
        hout[node * 32 + oc]      = __float2half(tanhf(acc0[r] + bi0));
        hout[node * 32 + 16 + oc] = __float2half(tanhf(acc1[r] + bi1));
    }
}

// ---------------- RGCN layers 1..3: 1-wave blocks, 64B-row gathers --------------
// 16 nodes / 64 threads: 6.7 KB LDS -> 24 blocks/CU = 24 waves/CU (vs ~12 at the
// R2 2-wave shape) -> ~2x memory-level parallelism for the latency-bound gather.
static __global__ __launch_bounds__(64, 6) void k_layer(
    const __half* __restrict__ tab, const int* __restrict__ offs,
    const int* __restrict__ cnt, const int* __restrict__ srcs,
    const __half* __restrict__ Wbl, const float* __restrict__ bias,
    __half* __restrict__ hout) {
    __shared__ __align__(16) __half sAgg[16 * ASTR];   // 6656 B
    int lane = threadIdx.x;
    int nsub = lane >> 2, cp = lane & 3;
    int n = blockIdx.x * 16 + nsub;                    // 6250*16 = 100000
    const half8* tab8 = (const half8*)tab;

    int s5 = n * N_REL;
    int o0 = offs[s5];
    int cc[5];
#pragma unroll
    for (int r = 0; r < 5; r++) cc[r] = cnt[s5 + r];

    __half* row = sAgg + nsub * ASTR;
    *(half8*)(row + 160 + cp * 8) = tab8[n * 4 + cp];  // self slot

    int ob[5];
    {
        int orun = o0;
#pragma unroll
        for (int r = 0; r < 5; r++) { ob[r] = orun; orun += (cc[r] + 7) & ~7; }
    }
    int4 E0[5], E1[5];
#pragma unroll
    for (int r = 0; r < 5; r++) {
        const int* sp = srcs + ob[r];
        E0[r] = *(const int4*)(sp);
        E1[r] = *(const int4*)(sp + 4);
    }
#pragma unroll
    for (int r = 0; r < 5; r++) {
        int cr = cc[r];
        int pr = (cr + 7) & ~7;
        const int* sp = srcs + ob[r];
        half8 g0 = tab8[E0[r].x * 4 + cp], g1 = tab8[E0[r].y * 4 + cp];
        half8 g2 = tab8[E0[r].z * 4 + cp], g3 = tab8[E0[r].w * 4 + cp];
        half8 g4 = tab8[E1[r].x * 4 + cp], g5 = tab8[E1[r].y * 4 + cp];
        half8 g6 = tab8[E1[r].z * 4 + cp], g7 = tab8[E1[r].w * 4 + cp];
        half8 sb = ((g0 + g1) + (g2 + g3)) + ((g4 + g5) + (g6 + g7));
        float S0 = (float)sb[0], S1 = (float)sb[1], S2 = (float)sb[2], S3 = (float)sb[3];
        float S4 = (float)sb[4], S5 = (float)sb[5], S6 = (float)sb[6], S7 = (float)sb[7];
        for (int s8 = 8; s8 < pr; s8 += 8) {
            int4 f0 = *(const int4*)(sp + s8);
            int4 f1 = *(const int4*)(sp + s8 + 4);
            half8 h0 = tab8[f0.x * 4 + cp], h1 = tab8[f0.y * 4 + cp];
            half8 h2 = tab8[f0.z * 4 + cp], h3 = tab8[f0.w * 4 + cp];
            half8 h4 = tab8[f1.x * 4 + cp], h5 = tab8[f1.y * 4 + cp];
            half8 h6 = tab8[f1.z * 4 + cp], h7 = tab8[f1.w * 4 + cp];
            half8 rb = ((h0 + h1) + (h2 + h3)) + ((h4 + h5) + (h6 + h7));
            S0 += (float)rb[0]; S1 += (float)rb[1]; S2 += (float)rb[2]; S3 += (float)rb[3];
            S4 += (float)rb[4]; S5 += (float)rb[5]; S6 += (float)rb[6]; S7 += (float)rb[7];
        }
        float ic = (cr > 0) ? __builtin_amdgcn_rcpf((float)cr) : 0.f;
        half8 u;
        u[0] = (_Float16)(S0 * ic); u[1] = (_Float16)(S1 * ic);
        u[2] = (_Float16)(S2 * ic); u[3] = (_Float16)(S3 * ic);
        u[4] = (_Float16)(S4 * ic); u[5] = (_Float16)(S5 * ic);
        u[6] = (_Float16)(S6 * ic); u[7] = (_Float16)(S7 * ic);
        *(half8*)(row + r * 32 + cp * 8) = u;
    }
    __syncthreads();

    floatx4 acc0 = {0.f, 0.f, 0.f, 0.f}, acc1 = {0.f, 0.f, 0.f, 0.f};
    const __half* aBase = sAgg + (lane & 15) * ASTR + ((lane >> 4) << 3);
    const __half* bBase = Wbl + lane * 8;
#pragma unroll
    for (int s = 0; s < 6; s++) {
        half8 a  = *(const half8*)(aBase + s * 32);
        half8 f0 = *(const half8*)(bBase + (s * 2 + 0) * 512);
        half8 f1 = *(const half8*)(bBase + (s * 2 + 1) * 512);
        acc0 = __builtin_amdgcn_mfma_f32_16x16x32_f16(a, f0, acc0, 0, 0, 0);
        acc1 = __builtin_amdgcn_mfma_f32_16x16x32_f16(a, f1, acc1, 0, 0, 0);
    }
    int oc = lane & 15;
    float bi0 = bias[oc], bi1 = bias[16 + oc];
#pragma unroll
    for (int r = 0; r < 4; r++) {
        int node = blockIdx.x * 16 + ((lane >> 4) << 2) + r;
        hout[node * 32 + oc]      = __float2half(tanhf(acc0[r] + bi0));
        hout[node * 32 + 16 + oc] = __float2half(tanhf(acc1[r] + bi1));
    }
}

// ---------------- final MLP via MFMA: 16 graphs/block ----------------
static __global__ __launch_bounds__(256) void k_mlp(
    const __half* __restrict__ h1, const __half* __restrict__ h2,
    const __half* __restrict__ h3, const __half* __restrict__ h4,
    const int* __restrict__ uidx, const int* __restrict__ iidx,
    const __half* __restrict__ Wm, const float* __restrict__ b1,
    const float* __restrict__ w2, const float* __restrict__ b2,
    float* __restrict__ out) {
    __shared__ __align__(16) __half sg[16 * 264];   // 8.25 KB
    __shared__ float sacc[4][16];
    int t = threadIdx.x, wave = t >> 6, lane = t & 63;
    int g0 = blockIdx.x * 16;
    int lt = lane >> 4, lp = lane & 15;
    const __half* htab = (lt == 0) ? h1 : (lt == 1) ? h2 : (lt == 2) ? h3 : h4;
#pragma unroll
    for (int gg2 = 0; gg2 < 4; gg2++) {
        int gg = wave * 4 + gg2;
        int g = g0 + gg;
        int u = uidx[g], it = iidx[g];
        __half2* dst = (__half2*)(sg + gg * 264);
        dst[lt * 16 + lp]      = ((const __half2*)(htab + u * 32))[lp];
        dst[64 + lt * 16 + lp] = ((const __half2*)(htab + it * 32))[lp];
    }
    __syncthreads();
    floatx4 acc0 = {0.f, 0.f, 0.f, 0.f}, acc1 = {0.f, 0.f, 0.f, 0.f};
    const __half* aBase = sg + (lane & 15) * 264 + ((lane >> 4) << 3);
    const __half* bB0 = Wm + (wave * 2 + 0) * 4096 + lane * 8;
    const __half* bB1 = Wm + (wave * 2 + 1) * 4096 + lane * 8;
#pragma unroll
    for (int s = 0; s < 8; s++) {
        half8 a  = *(const half8*)(aBase + s * 32);
        half8 f0 = *(const half8*)(bB0 + s * 512);
        half8 f1 = *(const half8*)(bB1 + s * 512);
        acc0 = __builtin_amdgcn_mfma_f32_16x16x32_f16(a, f0, acc0, 0, 0, 0);
        acc1 = __builtin_amdgcn_mfma_f32_16x16x32_f16(a, f1, acc1, 0, 0, 0);
    }
    int o0 = wave * 32 + (lane & 15);
    int o1 = o0 + 16;
    float b10 = b1[o0], b11 = b1[o1], w20 = w2[o0], w21 = w2[o1];
#pragma unroll
    for (int r = 0; r < 4; r++) {
        float z0 = fmaxf(acc0[r] + b10, 0.f);
        float z1 = fmaxf(acc1[r] + b11, 0.f);
        float v = z0 * w20 + z1 * w21;
#pragma unroll
        for (int off = 1; off < 16; off <<= 1) v += __shfl_xor(v, off);
        if ((lane & 15) == 0) sacc[wave][((lane >> 4) << 2) + r] = v;
    }
    __syncthreads();
    if (t < 16)
        out[g0 + t] = sacc[0][t] + sacc[1][t] + sacc[2][t] + sacc[3][t] + b2[0];
}

// ---------------- launcher ----------------
extern "C" void kernel_launch(void* const* d_in, const int* in_sizes, int n_in,
                              void* d_out, int out_size, void* d_ws, size_t ws_size,
                              hipStream_t stream) {
    const float* x  = (const float*)d_in[0];
    const int*   ei = (const int*)d_in[1];
    const int*   et = (const int*)d_in[2];
    const int*   ui = (const int*)d_in[3];
    const int*   ii = (const int*)d_in[4];
    const float* w1 = (const float*)d_in[21];
    const float* b1 = (const float*)d_in[22];
    const float* w2 = (const float*)d_in[23];
    const float* b2 = (const float*)d_in[24];

    // workspace layout (bytes, 128-aligned).
    char* ws = (char*)d_ws;
    if (ws_size < 92167680UL) return;
    int*    gcur = (int*)(ws + 0);              // [511]
    int*    offs = (int*)(ws + 2048);           // [500000]
    int*    cnt  = (int*)(ws + 2002176);        // [500000]
    int*    srcs = (int*)(ws + 4002304);        // [511*10752] + 16 slack, ends ~25.98MB
    __half* Wb   = (__half*)(ws + 26079488);    // [24576] fp16 RGCN B-frags (K=192)
    __half* Wm   = (__half*)(ws + 26128640);    // [32768] fp16 MLP B-frags
    __half* xt   = (__half*)(ws + 26194176);    // [100001*4] compact layer-0 table
    __half* ht1  = (__half*)(ws + 26994304);    // [100001*32]
    __half* ht2  = (__half*)(ws + 33394432);    // [100001*32]
    __half* ht3  = (__half*)(ws + 39794560);    // [100001*32]
    __half* ht4  = (__half*)(ws + 46194688);    // [100001*32], ends ~52.6MB
    // part aliases ht1.. (dead after k_bsort; layers run later): 511*7168*8 = 29.3MB
    unsigned long long* part = (unsigned long long*)(ws + 26994304);  // ends ~56.3MB

    hipMemsetAsync(gcur, 0, NBUCK * 4, stream);

    k_part<<<(N_EDGES + PTILE - 1) / PTILE, 256, 0, stream>>>(ei, et, gcur, part);
    k_bsort<<<NBUCK, 1024, 0, stream>>>(part, gcur, offs, cnt, srcs);
    k_prep<<<1788, 256, 0, stream>>>(           // 1563 xt + 1 pad + 96 wprepB + 128 wprepM
        x, xt, ht1, ht2, ht3, ht4, srcs,
        (const float*)d_in[5],  (const float*)d_in[6],  (const float*)d_in[7],
        (const float*)d_in[9],  (const float*)d_in[10], (const float*)d_in[11],
        (const float*)d_in[13], (const float*)d_in[14], (const float*)d_in[15],
        (const float*)d_in[17], (const float*)d_in[18], (const float*)d_in[19],
        Wb, w1, Wm);

    k_layer0<<<N_NODES / 16, 64, 0, stream>>>(
        xt, offs, cnt, srcs, Wb, (const float*)d_in[8], ht1);
    __half* tabs[4] = {ht1, ht2, ht3, ht4};
    for (int l = 1; l < 4; l++) {
        const float* bias = (const float*)d_in[8 + 4 * l];
        k_layer<<<N_NODES / 16, 64, 0, stream>>>(
            tabs[l - 1], offs, cnt, srcs, Wb + l * 6144, bias, tabs[l]);
    }
    k_mlp<<<256, 256, 0, stream>>>(ht1, ht2, ht3, ht4, ui, ii, Wm, b1, w2, b2,
                                   (float*)d_out);
}

// Round 7
// 316.594 us; speedup vs baseline: 1.1305x; 1.0969x over previous
//
#include <hip/hip_runtime.h>
#include <hip/hip_bf16.h>
#include <hip/hip_fp16.h>

#define N_NODES 100000
#define N_EDGES 3200000
#define N_GRAPHS 4096
#define N_REL 5
#define N_BASES 4
#define HID 32
#define SEG (N_NODES*N_REL)
#define DUMMY N_NODES            // extra node whose feature row is all-zero

#define BNODE 196                // dst nodes per bucket
#define NBUCK 511                // ceil(100000/196)
#define BCAP  7168               // part-record capacity per bucket (mean 6272)
#define PBCAP 10752              // padded srcs capacity per bucket (mean ~9.4K)
#define NKEY  980                // 196 nodes * 5 rels
#define PTILE 4096               // edges per k_part block

#define KDIM 192                 // MFMA K: 5 rel means * 32 + 32 self
#define ASTR 208                 // sAgg row stride in halves (416 B: 16B-aligned)

typedef _Float16 half8 __attribute__((ext_vector_type(8)));
typedef _Float16 half4 __attribute__((ext_vector_type(4)));
typedef float floatx4 __attribute__((ext_vector_type(4)));

__device__ inline half4 qshfl_xor(half4 v, int m) {
    union U { half4 h; long long l; } u; u.h = v;
    u.l = __shfl_xor(u.l, m);
    return u.h;
}
__device__ inline int qsel(int cp, int4 v) {
    int a = (cp & 1) ? v.y : v.x;
    int b = (cp & 1) ? v.w : v.z;
    return (cp & 2) ? b : a;
}

// ---------------- CSR pass 1 (R4-proven): partition edges into dst-range buckets ----
static __global__ __launch_bounds__(256) void k_part(const int* __restrict__ ei,
                                                     const int* __restrict__ et,
                                                     int* __restrict__ gcur,
                                                     unsigned long long* __restrict__ part) {
    __shared__ unsigned long long stage[PTILE];     // 32 KB
    __shared__ int hist[NBUCK];                     // 2 KB
    __shared__ int lofs[NBUCK];
    __shared__ int lbase[NBUCK];
    __shared__ int sscan[256];
    int t = threadIdx.x;
    int e0 = blockIdx.x * PTILE;
    int tile_n = N_EDGES - e0; if (tile_n > PTILE) tile_n = PTILE;

    for (int k = t; k < NBUCK; k += 256) hist[k] = 0;
    __syncthreads();
    int src[16], bkt[16], lkey[16];
#pragma unroll
    for (int j = 0; j < 16; j++) {
        int e = e0 + j * 256 + t;
        if (e < N_EDGES) {
            int s = ei[e];
            int d = ei[N_EDGES + e];
            int r = et[e];
            int bb = d / BNODE;                     // magic-mul const div
            src[j] = s; bkt[j] = bb; lkey[j] = (d - bb * BNODE) * 5 + r;
            atomicAdd(&hist[bb], 1);
        } else bkt[j] = -1;
    }
    __syncthreads();
    int h0 = (2 * t     < NBUCK) ? hist[2 * t]     : 0;
    int h1 = (2 * t + 1 < NBUCK) ? hist[2 * t + 1] : 0;
    int s2 = h0 + h1;
    sscan[t] = s2;
    __syncthreads();
    for (int off = 1; off < 256; off <<= 1) {
        int xv = (t >= off) ? sscan[t - off] : 0;
        __syncthreads();
        sscan[t] += xv;
        __syncthreads();
    }
    int excl = sscan[t] - s2;
    if (2 * t     < NBUCK) lofs[2 * t]     = excl;
    if (2 * t + 1 < NBUCK) lofs[2 * t + 1] = excl + h0;
    for (int k = t; k < NBUCK; k += 256) lbase[k] = atomicAdd(&gcur[k], hist[k]);
    __syncthreads();
    for (int k = t; k < NBUCK; k += 256) hist[k] = 0;   // reuse as cursor
    __syncthreads();
#pragma unroll
    for (int j = 0; j < 16; j++) {
        if (bkt[j] >= 0) {
            int rank = atomicAdd(&hist[bkt[j]], 1);
            stage[lofs[bkt[j]] + rank] =
                ((unsigned long long)(unsigned)((bkt[j] << 16) | lkey[j]) << 32)
                | (unsigned)src[j];
        }
    }
    __syncthreads();
    for (int i = t; i < tile_n; i += 256) {
        unsigned long long u = stage[i];
        unsigned hi = (unsigned)(u >> 32);
        int bb = hi >> 16;
        unsigned long long lk = hi & 0xFFFFu;
        int pos = lbase[bb] + (i - lofs[bb]);
        if (pos < BCAP)
            part[(size_t)bb * BCAP + pos] = (lk << 32) | (u & 0xffffffffULL);
    }
}

// ---------------- CSR pass 2 (R4-proven): per-bucket sort, LDS-staged copy-out ----
static __global__ __launch_bounds__(1024) void k_bsort(const unsigned long long* __restrict__ part,
                                                       const int* __restrict__ gcur,
                                                       int* __restrict__ offs,
                                                       int* __restrict__ cnt,
                                                       int* __restrict__ srcs) {
    __shared__ int lhist[NKEY];      // 3.9 KB
    __shared__ int lscan[NKEY];      // 3.9 KB
    __shared__ int sscan[256];       // 1 KB
    __shared__ int lsrc[PBCAP];      // 42 KB
    int b = blockIdx.x;
    int t = threadIdx.x;
    int n = gcur[b]; if (n > BCAP) n = BCAP;
    const unsigned long long* reg = part + (size_t)b * BCAP;

    for (int k = t; k < NKEY; k += 1024) lhist[k] = 0;
    __syncthreads();
    for (int i = t; i < n; i += 1024)
        atomicAdd(&lhist[(int)(reg[i] >> 32)], 1);
    __syncthreads();

    int loc[5]; int s5 = 0;
    if (t < 196) {
#pragma unroll
        for (int j = 0; j < 5; j++) { loc[j] = s5; s5 += (lhist[t * 5 + j] + 7) & ~7; }
    }
    if (t < 256) sscan[t] = (t < 196) ? s5 : 0;
    __syncthreads();
    for (int off = 1; off < 256; off <<= 1) {
        int x = (t >= off && t < 256) ? sscan[t - off] : 0;
        __syncthreads();
        if (t < 256) sscan[t] += x;
        __syncthreads();
    }
    if (t < 196) {
        int excl = sscan[t] - s5;
#pragma unroll
        for (int j = 0; j < 5; j++) lscan[t * 5 + j] = excl + loc[j];
    }
    __syncthreads();
    int ptot = sscan[255]; if (ptot > PBCAP) ptot = PBCAP;
    int pout = ptot + 16; if (pout > PBCAP) pout = PBCAP;

    int base = b * PBCAP;
    if (t < 196) {
#pragma unroll
        for (int j = 0; j < 5; j++) {
            int k = t * 5 + j;
            int segid = b * NKEY + k;               // = (b*196+t)*5 + j
            if (segid < SEG) {
                cnt[segid]  = lhist[k];
                offs[segid] = base + lscan[k];
            }
        }
    }
    __syncthreads();
    for (int k = t; k < NKEY; k += 1024) lhist[k] = 0;
    for (int i = t; i < pout; i += 1024) lsrc[i] = DUMMY;
    __syncthreads();
    for (int i = t; i < n; i += 1024) {
        unsigned long long u = reg[i];
        int k = (int)(u >> 32);
        int pos = lscan[k] + atomicAdd(&lhist[k], 1);
        if (pos < PBCAP) lsrc[pos] = (int)(u & 0xffffffffULL);
    }
    __syncthreads();
    for (int i = t; i < pout; i += 1024) srcs[base + i] = lsrc[i];
}

// ---------------- merged prep: compact xt table + pads + B-frags ----------------
static __global__ __launch_bounds__(256) void k_prep(
    const float* __restrict__ x, __half* __restrict__ xt,
    __half* __restrict__ ht1, __half* __restrict__ ht2,
    __half* __restrict__ ht3, __half* __restrict__ ht4, int* __restrict__ srcs,
    const float* __restrict__ ba0, const float* __restrict__ co0, const float* __restrict__ ro0,
    const float* __restrict__ ba1, const float* __restrict__ co1, const float* __restrict__ ro1,
    const float* __restrict__ ba2, const float* __restrict__ co2, const float* __restrict__ ro2,
    const float* __restrict__ ba3, const float* __restrict__ co3, const float* __restrict__ ro3,
    __half* __restrict__ Wb, const float* __restrict__ w1, __half* __restrict__ Wm) {
    int blk = blockIdx.x;
    int t = threadIdx.x;
    if (blk < 1563) {
        int tid = blk * 256 + t;                    // < (N+1)*4 = 400004
        if (tid < (N_NODES + 1) * 4) {
            float v = (tid < N_NODES * 4) ? x[tid] : 0.f;
            xt[tid] = __float2half(v);
        }
    } else if (blk == 1563) {
        if (t < 128) {
            __half* hp = (t < 32) ? ht1 : (t < 64) ? ht2 : (t < 96) ? ht3 : ht4;
            hp[N_NODES * 32 + (t & 31)] = __float2half(0.f);   // dummy rows
        } else if (t < 144) srcs[NBUCK * PBCAP + (t - 128)] = DUMMY;  // slack
    } else if (blk < 1564 + 96) {
        // ---- RGCN fp16 B-fragments, K=192, comp folded (24576 threads) ----
        int idx = (blk - 1564) * 256 + t;
        int j    = idx & 7;
        int lane = (idx >> 3) & 63;
        int tile = (idx >> 9) & 1;
        int ls   = idx >> 10;                       // l*6 + s, < 24
        int l    = ls / 6;
        int s    = ls - l * 6;
        const float* basis = (l == 0) ? ba0 : (l == 1) ? ba1 : (l == 2) ? ba2 : ba3;
        const float* comp  = (l == 0) ? co0 : (l == 1) ? co1 : (l == 2) ? co2 : co3;
        const float* root  = (l == 0) ? ro0 : (l == 1) ? ro1 : (l == 2) ? ro2 : ro3;
        int in_c = (l == 0) ? 4 : HID;
        int d = ((lane >> 4) << 3) + j;             // dim within slot, 0..31
        int o = tile * 16 + (lane & 15);
        float v = 0.f;
        if (d < in_c) {
            if (s < 5) {
                float acc = 0.f;
#pragma unroll
                for (int b = 0; b < N_BASES; b++)
                    acc += comp[s * N_BASES + b] * basis[(b * in_c + d) * HID + o];
                v = acc;
            } else {
                v = root[d * HID + o];
            }
        }
        Wb[idx] = __float2half(v);
    } else {
        // ---- w1 [256x128] fp16 B-fragments (32768 threads) ----
        int idx = (blk - 1660) * 256 + t;
        int j    = idx & 7;
        int lane = (idx >> 3) & 63;
        int s    = (idx >> 9) & 7;
        int tile = idx >> 12;                       // < 8
        int k = s * 32 + ((lane >> 4) << 3) + j;
        int o = tile * 16 + (lane & 15);
        Wm[idx] = __float2half(w1[k * 128 + o]);
    }
}

// ---------------- RGCN layer 0: compact 8B-row gathers, proven 2-wave shape -----
// 32 nodes / 128 threads (13.3 KB LDS — R2/R4-proven residency). Per batch of 8
// edges, lane cp loads 2 half4 rows from the 800 KB L2-resident xt; quad
// shfl-reduce -> fp32 across batches. Only dims 0..3 of each K slot written;
// rest zeroed once (Wb layer-0 weights are 0 there).
static __global__ __launch_bounds__(128, 5) void k_layer0(
    const __half* __restrict__ xt, const int* __restrict__ offs,
    const int* __restrict__ cnt, const int* __restrict__ srcs,
    const __half* __restrict__ Wbl, const float* __restrict__ bias,
    __half* __restrict__ hout) {
    __shared__ __align__(16) __half sAgg[32 * ASTR];   // 13.3 KB
    int t = threadIdx.x;
    int wave = t >> 6, lane = t & 63;
    int nsub = lane >> 2, cp = lane & 3;
    int nl = wave * 16 + nsub;                         // LDS row 0..31
    int n = blockIdx.x * 32 + nl;                      // 3125*32 = 100000
    const half4* xt4 = (const half4*)xt;

    half8 z = {};
    for (int i = t; i < 32 * ASTR / 8; i += 128) ((half8*)sAgg)[i] = z;

    int s5 = n * N_REL;
    int o0 = offs[s5];
    int cc[5];
#pragma unroll
    for (int r = 0; r < 5; r++) cc[r] = cnt[s5 + r];
    int ob[5];
    {
        int orun = o0;
#pragma unroll
        for (int r = 0; r < 5; r++) { ob[r] = orun; orun += (cc[r] + 7) & ~7; }
    }
    int4 E0[5], E1[5];
#pragma unroll
    for (int r = 0; r < 5; r++) {
        const int* sp = srcs + ob[r];
        E0[r] = *(const int4*)(sp);
        E1[r] = *(const int4*)(sp + 4);
    }
    half4 selfv = xt4[n];
    __syncthreads();                                   // zero-fill visible

    __half* row = sAgg + nl * ASTR;
    if (cp == 0) *(half4*)(row + 160) = selfv;         // self slot, dims 0..3

#pragma unroll
    for (int r = 0; r < 5; r++) {
        int cr = cc[r];
        int pr = (cr + 7) & ~7;
        const int* sp = srcs + ob[r];
        half4 xa = xt4[qsel(cp, E0[r])];
        half4 xb = xt4[qsel(cp, E1[r])];
        half4 hs = xa + xb;
        hs += qshfl_xor(hs, 1);
        hs += qshfl_xor(hs, 2);
        float S0 = (float)hs[0], S1 = (float)hs[1], S2 = (float)hs[2], S3 = (float)hs[3];
        for (int s8 = 8; s8 < pr; s8 += 8) {
            int4 f0 = *(const int4*)(sp + s8);
            int4 f1 = *(const int4*)(sp + s8 + 4);
            half4 ya = xt4[qsel(cp, f0)];
            half4 yb = xt4[qsel(cp, f1)];
            half4 rs = ya + yb;
            rs += qshfl_xor(rs, 1);
            rs += qshfl_xor(rs, 2);
            S0 += (float)rs[0]; S1 += (float)rs[1]; S2 += (float)rs[2]; S3 += (float)rs[3];
        }
        float ic = (cr > 0) ? __builtin_amdgcn_rcpf((float)cr) : 0.f;
        if (cp == 0) {
            half4 u;
            u[0] = (_Float16)(S0 * ic); u[1] = (_Float16)(S1 * ic);
            u[2] = (_Float16)(S2 * ic); u[3] = (_Float16)(S3 * ic);
            *(half4*)(row + r * 32) = u;               // slot r, dims 0..3
        }
    }
    __syncthreads();

    floatx4 acc0 = {0.f, 0.f, 0.f, 0.f}, acc1 = {0.f, 0.f, 0.f, 0.f};
    const __half* aBase = sAgg + (wave * 16 + (lane & 15)) * ASTR + ((lane >> 4) << 3);
    const __half* bBase = Wbl + lane * 8;
#pragma unroll
    for (int s = 0; s < 6; s++) {
        half8 a  = *(const half8*)(aBase + s * 32);
        half8 f0 = *(const half8*)(bBase + (s * 2 + 0) * 512);
        half8 f1 = *(const half8*)(bBase + (s * 2 + 1) * 512);
        acc0 = __builtin_amdgcn_mfma_f32_16x16x32_f16(a, f0, acc0, 0, 0, 0);
        acc1 = __builtin_amdgcn_mfma_f32_16x16x32_f16(a, f1, acc1, 0, 0, 0);
    }
    int oc = lane & 15;
    float bi0 = bias[oc], bi1 = bias[16 + oc];
#pragma unroll
    for (int r = 0; r < 4; r++) {
        int node = blockIdx.x * 32 + wave * 16 + ((lane >> 4) << 2) + r;
        hout[node * 32 + oc]      = __float2half(tanhf(acc0[r] + bi0));
        hout[node * 32 + 16 + oc] = __float2half(tanhf(acc1[r] + bi1));
    }
}

// ---------------- RGCN layers 1..3 (exact R2/R4-proven 2-wave version) ----------
static __global__ __launch_bounds__(128, 5) void k_layer(
    const __half* __restrict__ tab, const int* __restrict__ offs,
    const int* __restrict__ cnt, const int* __restrict__ srcs,
    const __half* __restrict__ Wbl, const float* __restrict__ bias,
    __half* __restrict__ hout) {
    __shared__ __align__(16) __half sAgg[32 * ASTR];   // 13.3 KB
    int t = threadIdx.x;
    int wave = t >> 6, lane = t & 63;
    int nsub = lane >> 2, cp = lane & 3;               // node-in-wave, 16B chunk
    int nl = wave * 16 + nsub;                         // LDS row 0..31
    int n = blockIdx.x * 32 + nl;                      // exact: 3125*32 = 100000
    const half8* tab8 = (const half8*)tab;

    int s5 = n * N_REL;
    int o0 = offs[s5];
    int cc[5];
#pragma unroll
    for (int r = 0; r < 5; r++) cc[r] = cnt[s5 + r];

    __half* row = sAgg + nl * ASTR;
    *(half8*)(row + 160 + cp * 8) = tab8[n * 4 + cp];  // self slot

    int ob[5];
    {
        int orun = o0;
#pragma unroll
        for (int r = 0; r < 5; r++) { ob[r] = orun; orun += (cc[r] + 7) & ~7; }
    }
    int4 E0[5], E1[5];
#pragma unroll
    for (int r = 0; r < 5; r++) {
        const int* sp = srcs + ob[r];
        E0[r] = *(const int4*)(sp);
        E1[r] = *(const int4*)(sp + 4);
    }
#pragma unroll
    for (int r = 0; r < 5; r++) {
        int cr = cc[r];
        int pr = (cr + 7) & ~7;
        const int* sp = srcs + ob[r];
        half8 g0 = tab8[E0[r].x * 4 + cp], g1 = tab8[E0[r].y * 4 + cp];
        half8 g2 = tab8[E0[r].z * 4 + cp], g3 = tab8[E0[r].w * 4 + cp];
        half8 g4 = tab8[E1[r].x * 4 + cp], g5 = tab8[E1[r].y * 4 + cp];
        half8 g6 = tab8[E1[r].z * 4 + cp], g7 = tab8[E1[r].w * 4 + cp];
        half8 sb = ((g0 + g1) + (g2 + g3)) + ((g4 + g5) + (g6 + g7));
        float S0 = (float)sb[0], S1 = (float)sb[1], S2 = (float)sb[2], S3 = (float)sb[3];
        float S4 = (float)sb[4], S5 = (float)sb[5], S6 = (float)sb[6], S7 = (float)sb[7];
        for (int s8 = 8; s8 < pr; s8 += 8) {
            int4 f0 = *(const int4*)(sp + s8);
            int4 f1 = *(const int4*)(sp + s8 + 4);
            half8 h0 = tab8[f0.x * 4 + cp], h1 = tab8[f0.y * 4 + cp];
            half8 h2 = tab8[f0.z * 4 + cp], h3 = tab8[f0.w * 4 + cp];
            half8 h4 = tab8[f1.x * 4 + cp], h5 = tab8[f1.y * 4 + cp];
            half8 h6 = tab8[f1.z * 4 + cp], h7 = tab8[f1.w * 4 + cp];
            half8 rb = ((h0 + h1) + (h2 + h3)) + ((h4 + h5) + (h6 + h7));
            S0 += (float)rb[0]; S1 += (float)rb[1]; S2 += (float)rb[2]; S3 += (float)rb[3];
            S4 += (float)rb[4]; S5 += (float)rb[5]; S6 += (float)rb[6]; S7 += (float)rb[7];
        }
        float ic = (cr > 0) ? __builtin_amdgcn_rcpf((float)cr) : 0.f;
        half8 u;
        u[0] = (_Float16)(S0 * ic); u[1] = (_Float16)(S1 * ic);
        u[2] = (_Float16)(S2 * ic); u[3] = (_Float16)(S3 * ic);
        u[4] = (_Float16)(S4 * ic); u[5] = (_Float16)(S5 * ic);
        u[6] = (_Float16)(S6 * ic); u[7] = (_Float16)(S7 * ic);
        *(half8*)(row + r * 32 + cp * 8) = u;
    }
    __syncthreads();

    floatx4 acc0 = {0.f, 0.f, 0.f, 0.f}, acc1 = {0.f, 0.f, 0.f, 0.f};
    const __half* aBase = sAgg + (wave * 16 + (lane & 15)) * ASTR + ((lane >> 4) << 3);
    const __half* bBase = Wbl + lane * 8;
#pragma unroll
    for (int s = 0; s < 6; s++) {
        half8 a  = *(const half8*)(aBase + s * 32);
        half8 f0 = *(const half8*)(bBase + (s * 2 + 0) * 512);
        half8 f1 = *(const half8*)(bBase + (s * 2 + 1) * 512);
        acc0 = __builtin_amdgcn_mfma_f32_16x16x32_f16(a, f0, acc0, 0, 0, 0);
        acc1 = __builtin_amdgcn_mfma_f32_16x16x32_f16(a, f1, acc1, 0, 0, 0);
    }
    int oc = lane & 15;
    float bi0 = bias[oc], bi1 = bias[16 + oc];
#pragma unroll
    for (int r = 0; r < 4; r++) {
        int node = blockIdx.x * 32 + wave * 16 + ((lane >> 4) << 2) + r;
        hout[node * 32 + oc]      = __float2half(tanhf(acc0[r] + bi0));
        hout[node * 32 + 16 + oc] = __float2half(tanhf(acc1[r] + bi1));
    }
}

// ---------------- final MLP via MFMA: 16 graphs/block ----------------
static __global__ __launch_bounds__(256) void k_mlp(
    const __half* __restrict__ h1, const __half* __restrict__ h2,
    const __half* __restrict__ h3, const __half* __restrict__ h4,
    const int* __restrict__ uidx, const int* __restrict__ iidx,
    const __half* __restrict__ Wm, const float* __restrict__ b1,
    const float* __restrict__ w2, const float* __restrict__ b2,
    float* __restrict__ out) {
    __shared__ __align__(16) __half sg[16 * 264];   // 8.25 KB
    __shared__ float sacc[4][16];
    int t = threadIdx.x, wave = t >> 6, lane = t & 63;
    int g0 = blockIdx.x * 16;
    int lt = lane >> 4, lp = lane & 15;
    const __half* htab = (lt == 0) ? h1 : (lt == 1) ? h2 : (lt == 2) ? h3 : h4;
#pragma unroll
    for (int gg2 = 0; gg2 < 4; gg2++) {
        int gg = wave * 4 + gg2;
        int g = g0 + gg;
        int u = uidx[g], it = iidx[g];
        __half2* dst = (__half2*)(sg + gg * 264);
        dst[lt * 16 + lp]      = ((const __half2*)(htab + u * 32))[lp];
        dst[64 + lt * 16 + lp] = ((const __half2*)(htab + it * 32))[lp];
    }
    __syncthreads();
    floatx4 acc0 = {0.f, 0.f, 0.f, 0.f}, acc1 = {0.f, 0.f, 0.f, 0.f};
    const __half* aBase = sg + (lane & 15) * 264 + ((lane >> 4) << 3);
    const __half* bB0 = Wm + (wave * 2 + 0) * 4096 + lane * 8;
    const __half* bB1 = Wm + (wave * 2 + 1) * 4096 + lane * 8;
#pragma unroll
    for (int s = 0; s < 8; s++) {
        half8 a  = *(const half8*)(aBase + s * 32);
        half8 f0 = *(const half8*)(bB0 + s * 512);
        half8 f1 = *(const half8*)(bB1 + s * 512);
        acc0 = __builtin_amdgcn_mfma_f32_16x16x32_f16(a, f0, acc0, 0, 0, 0);
        acc1 = __builtin_amdgcn_mfma_f32_16x16x32_f16(a, f1, acc1, 0, 0, 0);
    }
    int o0 = wave * 32 + (lane & 15);
    int o1 = o0 + 16;
    float b10 = b1[o0], b11 = b1[o1], w20 = w2[o0], w21 = w2[o1];
#pragma unroll
    for (int r = 0; r < 4; r++) {
        float z0 = fmaxf(acc0[r] + b10, 0.f);
        float z1 = fmaxf(acc1[r] + b11, 0.f);
        float v = z0 * w20 + z1 * w21;
#pragma unroll
        for (int off = 1; off < 16; off <<= 1) v += __shfl_xor(v, off);
        if ((lane & 15) == 0) sacc[wave][((lane >> 4) << 2) + r] = v;
    }
    __syncthreads();
    if (t < 16)
        out[g0 + t] = sacc[0][t] + sacc[1][t] + sacc[2][t] + sacc[3][t] + b2[0];
}

// ---------------- launcher ----------------
extern "C" void kernel_launch(void* const* d_in, const int* in_sizes, int n_in,
                              void* d_out, int out_size, void* d_ws, size_t ws_size,
                              hipStream_t stream) {
    const float* x  = (const float*)d_in[0];
    const int*   ei = (const int*)d_in[1];
    const int*   et = (const int*)d_in[2];
    const int*   ui = (const int*)d_in[3];
    const int*   ii = (const int*)d_in[4];
    const float* w1 = (const float*)d_in[21];
    const float* b1 = (const float*)d_in[22];
    const float* w2 = (const float*)d_in[23];
    const float* b2 = (const float*)d_in[24];

    // workspace layout (bytes, 128-aligned).
    char* ws = (char*)d_ws;
    if (ws_size < 92167680UL) return;
    int*    gcur = (int*)(ws + 0);              // [511]
    int*    offs = (int*)(ws + 2048);           // [500000]
    int*    cnt  = (int*)(ws + 2002176);        // [500000]
    int*    srcs = (int*)(ws + 4002304);        // [511*10752] + 16 slack, ends ~25.98MB
    __half* Wb   = (__half*)(ws + 26079488);    // [24576] fp16 RGCN B-frags (K=192)
    __half* Wm   = (__half*)(ws + 26128640);    // [32768] fp16 MLP B-frags
    __half* xt   = (__half*)(ws + 26194176);    // [100001*4] compact layer-0 table
    __half* ht1  = (__half*)(ws + 26994304);    // [100001*32]
    __half* ht2  = (__half*)(ws + 33394432);    // [100001*32]
    __half* ht3  = (__half*)(ws + 39794560);    // [100001*32]
    __half* ht4  = (__half*)(ws + 46194688);    // [100001*32], ends ~52.6MB
    // part aliases ht1.. (dead after k_bsort; layers run later): 511*7168*8 = 29.3MB
    unsigned long long* part = (unsigned long long*)(ws + 26994304);  // ends ~56.3MB

    hipMemsetAsync(gcur, 0, NBUCK * 4, stream);

    k_part<<<(N_EDGES + PTILE - 1) / PTILE, 256, 0, stream>>>(ei, et, gcur, part);
    k_bsort<<<NBUCK, 1024, 0, stream>>>(part, gcur, offs, cnt, srcs);
    k_prep<<<1788, 256, 0, stream>>>(           // 1563 xt + 1 pad + 96 wprepB + 128 wprepM
        x, xt, ht1, ht2, ht3, ht4, srcs,
        (const float*)d_in[5],  (const float*)d_in[6],  (const float*)d_in[7],
        (const float*)d_in[9],  (const float*)d_in[10], (const float*)d_in[11],
        (const float*)d_in[13], (const float*)d_in[14], (const float*)d_in[15],
        (const float*)d_in[17], (const float*)d_in[18], (const float*)d_in[19],
        Wb, w1, Wm);

    k_layer0<<<N_NODES / 32, 128, 0, stream>>>(
        xt, offs, cnt, srcs, Wb, (const float*)d_in[8], ht1);
    __half* tabs[4] = {ht1, ht2, ht3, ht4};
    for (int l = 1; l < 4; l++) {
        const float* bias = (const float*)d_in[8 + 4 * l];
        k_layer<<<N_NODES / 32, 128, 0, stream>>>(
            tabs[l - 1], offs, cnt, srcs, Wb + l * 6144, bias, tabs[l]);
    }
    k_mlp<<<256, 256, 0, stream>>>(ht1, ht2, ht3, ht4, ui, ii, Wm, b1, w2, b2,
                                   (float*)d_out);
}